// Round 1
// baseline (37310.669 us; speedup 1.0000x reference)
//
#include <hip/hip_runtime.h>
#include <stdint.h>
#include <stdio.h>

// Problem constants
#define TL 1024          // T
#define BB 64            // B
#define HH 512           // H
#define II 1024          // input size (== 2H for layer 2)
#define NL 2             // layers
#define BT_ (BB*TL)      // 65536
#define G3_ 1536         // 3H
#define N2_ 3072         // 2*3H (both dirs stacked)

typedef _Float16 h8 __attribute__((ext_vector_type(8)));
typedef _Float16 h4 __attribute__((ext_vector_type(4)));
typedef float    f4 __attribute__((ext_vector_type(4)));
typedef unsigned int u4 __attribute__((ext_vector_type(4)));

// ---------------- fp32 -> fp16 convert ----------------
__global__ void cvt_f2h(const float* __restrict__ src, _Float16* __restrict__ dst, size_t n4) {
  size_t i = (size_t)blockIdx.x*blockDim.x + threadIdx.x;
  size_t stride = (size_t)gridDim.x*blockDim.x;
  for (; i < n4; i += stride) {
    f4 v = ((const f4*)src)[i];
    h4 o;
    o[0] = (_Float16)v[0]; o[1] = (_Float16)v[1];
    o[2] = (_Float16)v[2]; o[3] = (_Float16)v[3];
    ((h4*)dst)[i] = o;
  }
}

// ---------------- gi GEMM:  C[m,n] = sum_k A[m,k]*W[n,k] + bias[n] ----------------
// A: (65536 x 1024) fp16 row-major.  W: (3072 x 1024) fp16 row-major (both dirs stacked).
// Output gi layout: [dir][m][1536] fp16, m = b*T + t.
#define LDA 40   // padded LDS stride (halves); 80B rows keep 16B alignment, 2-way banks only
__launch_bounds__(256)
__global__ void gemm_gi(const _Float16* __restrict__ A, const _Float16* __restrict__ Bw,
                        const float* __restrict__ bias, _Float16* __restrict__ gi)
{
  const int bn = blockIdx.x, bm = blockIdx.y;
  const int tid = threadIdx.x;
  const int wave = tid >> 6, lane = tid & 63;
  const int wm = wave >> 1, wn = wave & 1;     // 2x2 waves -> 64x64 each
  const int lo = lane & 15, hi = lane >> 4;
  __shared__ _Float16 As[128*LDA];
  __shared__ _Float16 Bs[128*LDA];
  f4 acc[4][4] = {};
  const int r0 = tid >> 2, c0 = (tid & 3)*8;   // staging: rows r0 and r0+64, 8-half chunk c0
  const _Float16* Ag = A + (size_t)(bm*128)*II;
  const _Float16* Bg = Bw + (size_t)(bn*128)*II;
  u4 a0 = *(const u4*)(Ag + (size_t)r0*II + c0);
  u4 a1 = *(const u4*)(Ag + (size_t)(64+r0)*II + c0);
  u4 b0 = *(const u4*)(Bg + (size_t)r0*II + c0);
  u4 b1 = *(const u4*)(Bg + (size_t)(64+r0)*II + c0);
  for (int kt = 0; kt < 32; ++kt) {
    __syncthreads();
    *(u4*)&As[r0*LDA + c0] = a0;
    *(u4*)&As[(64+r0)*LDA + c0] = a1;
    *(u4*)&Bs[r0*LDA + c0] = b0;
    *(u4*)&Bs[(64+r0)*LDA + c0] = b1;
    if (kt+1 < 32) {
      const int off = (kt+1)*32 + c0;
      a0 = *(const u4*)(Ag + (size_t)r0*II + off);
      a1 = *(const u4*)(Ag + (size_t)(64+r0)*II + off);
      b0 = *(const u4*)(Bg + (size_t)r0*II + off);
      b1 = *(const u4*)(Bg + (size_t)(64+r0)*II + off);
    }
    __syncthreads();
    h8 af[4], bf[4];
    #pragma unroll
    for (int i = 0; i < 4; ++i)
      af[i] = *(const h8*)&As[(wm*64 + i*16 + lo)*LDA + hi*8];
    #pragma unroll
    for (int j = 0; j < 4; ++j)
      bf[j] = *(const h8*)&Bs[(wn*64 + j*16 + lo)*LDA + hi*8];
    #pragma unroll
    for (int i = 0; i < 4; ++i)
      #pragma unroll
      for (int j = 0; j < 4; ++j)
        acc[i][j] = __builtin_amdgcn_mfma_f32_16x16x32_f16(af[i], bf[j], acc[i][j], 0, 0, 0);
  }
  // epilogue: D row m = (lane>>4)*4+v, col n = lane&15  (verified layout)
  const int nbase = bn*128 + wn*64;
  const int mbase = bm*128 + wm*64;
  #pragma unroll
  for (int j = 0; j < 4; ++j) {
    int n = nbase + j*16 + lo;
    int dir = (n >= G3_) ? 1 : 0;
    int row = n - dir*G3_;
    float bs = bias[n];
    #pragma unroll
    for (int i = 0; i < 4; ++i) {
      int m0 = mbase + i*16 + hi*4;
      #pragma unroll
      for (int v = 0; v < 4; ++v)
        gi[((size_t)dir*BT_ + (size_t)(m0+v))*G3_ + row] = (_Float16)(acc[i][j][v] + bs);
    }
  }
}

// ---------------- persistent GRU layer kernel ----------------
// 128 blocks: group_global = bid&7 (same-XCD under round-robin dispatch): d = gg&1, g = gg>>1.
// member = bid>>3 (0..15) owns j-slice [member*32, +32) of H, all 3 gates (96 W_hh rows in LDS).
// Group = 16 blocks, owns batch chunk [g*16, +16). Sync: monotonic agent-scope counter.
#define LDW 520
__launch_bounds__(384, 1)
__global__ void gru_layer(const _Float16* __restrict__ gi,     // [dir][b*T+t][1536]
                          const _Float16* __restrict__ whh,    // layer: [dir][1536][512]
                          const float* __restrict__ bhh,       // layer: [dir][1536]
                          const float* __restrict__ h0,        // [4][64][512]
                          _Float16* __restrict__ h_buf,        // [dir][2][64][512]
                          unsigned* __restrict__ cnt,          // 8 counters, stride 32 uints
                          _Float16* __restrict__ out_mid,      // layer0: [b][t][1024] fp16
                          float* __restrict__ out_fin,         // layer1: [b][t][1024] fp32
                          float* __restrict__ hn_out,          // [4][64][512] fp32
                          int layer)
{
  const int bid = blockIdx.x;
  const int gg = bid & 7, d = gg & 1, g = gg >> 1;
  const int member = bid >> 3;
  const int j0 = member * 32, b0 = g * 16;
  const int tid = threadIdx.x;
  const int wave = tid >> 6, lane = tid & 63, lo = lane & 15, hi = lane >> 4;
  const int gate = wave >> 1, jh = wave & 1;     // 6 waves: 3 gates x 2 j-halves

  __shared__ _Float16 wlds[3][32][LDW];
  __shared__ _Float16 hlds[16][LDW];
  __shared__ float    ghlds[3][32][17];

  // --- load resident W_hh slice: rows gate*512 + j0 + jj ---
  const _Float16* wsrc = whh + (size_t)d*G3_*HH;
  #pragma unroll
  for (int it = 0; it < 16; ++it) {
    int idx = it*384 + tid;            // 6144 chunks of 8 halves (96 rows x 64 chunks)
    int row = idx >> 6;
    int c8 = (idx & 63) * 8;
    int gt = row >> 5, jj = row & 31;
    u4 v = *(const u4*)(wsrc + (size_t)(gt*HH + j0 + jj)*HH + c8);
    *(u4*)&wlds[gt][jj][c8] = v;
  }

  unsigned* mycnt = cnt + gg*32;       // 128B spacing between group counters
  const int ej = tid & 31;             // elementwise: thread owns (j=ej, b=eb0) and (j=ej, b=eb0+8)
  const int eb0 = tid >> 5;            // 0..7 for tid<256
  const bool ew = (tid < 256);
  float hreg[2];
  float bhr_ = 0.f, bhz_ = 0.f, bhn_ = 0.f;
  _Float16 gR[2], gZ[2], gN[2];

  if (ew) {
    bhr_ = bhh[(size_t)d*G3_ + 0*HH + j0 + ej];
    bhz_ = bhh[(size_t)d*G3_ + 1*HH + j0 + ej];
    bhn_ = bhh[(size_t)d*G3_ + 2*HH + j0 + ej];
    #pragma unroll
    for (int e = 0; e < 2; ++e) {
      int b = eb0 + e*8;
      hreg[e] = h0[((size_t)(2*layer + d)*BB + b0 + b)*HH + j0 + ej];
      h_buf[(((size_t)d*2 + 0)*BB + b0 + b)*HH + j0 + ej] = (_Float16)hreg[e];
    }
  }
  __syncthreads();
  if (tid == 0) {
    __threadfence();
    __hip_atomic_fetch_add(mycnt, 1u, __ATOMIC_RELEASE, __HIP_MEMORY_SCOPE_AGENT);
    while (__hip_atomic_load(mycnt, __ATOMIC_ACQUIRE, __HIP_MEMORY_SCOPE_AGENT) < 16u) {}
  }
  __syncthreads();
  __threadfence();

  for (int s = 0; s < TL; ++s) {
    const int t = d ? (TL-1 - s) : s;
    const int rpar = s & 1, wpar = rpar ^ 1;
    if (ew) {
      // gi prefetch for this step (stays in flight across raw barriers; used in elementwise)
      #pragma unroll
      for (int e = 0; e < 2; ++e) {
        const _Float16* p = gi + ((size_t)d*BT_ + (size_t)(b0 + eb0 + e*8)*TL + t)*(size_t)G3_ + j0 + ej;
        gR[e] = p[0]; gZ[e] = p[HH]; gN[e] = p[2*HH];
      }
      // stage h chunk (16 x 512) -> LDS
      const _Float16* hsrc = h_buf + (((size_t)d*2 + rpar)*BB + b0)*HH;
      #pragma unroll
      for (int it = 0; it < 4; ++it) {
        int idx = it*256 + tid;
        int r = idx >> 6, c8 = (idx & 63) * 8;
        u4 v = *(const u4*)(hsrc + (size_t)r*HH + c8);
        *(u4*)&hlds[r][c8] = v;
      }
    }
    asm volatile("s_waitcnt lgkmcnt(0)" ::: "memory");
    __builtin_amdgcn_s_barrier();
    __builtin_amdgcn_sched_barrier(0);
    // --- gh slice: (16b x 16j) per wave over K=512 ---
    f4 acc = {0.f, 0.f, 0.f, 0.f};
    #pragma unroll
    for (int kk = 0; kk < 16; ++kk) {
      h8 af = *(const h8*)&hlds[lo][kk*32 + hi*8];
      h8 bf = *(const h8*)&wlds[gate][jh*16 + lo][kk*32 + hi*8];
      acc = __builtin_amdgcn_mfma_f32_16x16x32_f16(af, bf, acc, 0, 0, 0);
    }
    #pragma unroll
    for (int v = 0; v < 4; ++v)
      ghlds[gate][jh*16 + lo][hi*4 + v] = acc[v];   // [gate][j][b]
    asm volatile("s_waitcnt lgkmcnt(0)" ::: "memory");
    __builtin_amdgcn_s_barrier();
    __builtin_amdgcn_sched_barrier(0);
    // --- elementwise GRU update ---
    if (ew) {
      #pragma unroll
      for (int e = 0; e < 2; ++e) {
        int b = eb0 + e*8;
        float ir = (float)gR[e], iz = (float)gZ[e], inn = (float)gN[e];
        float hr = ghlds[0][ej][b] + bhr_;
        float hz = ghlds[1][ej][b] + bhz_;
        float hn = ghlds[2][ej][b] + bhn_;
        float rr = 1.f/(1.f + expf(-(ir + hr)));
        float zz = 1.f/(1.f + expf(-(iz + hz)));
        float nn = tanhf(inn + rr*hn);
        float h  = (1.f - zz)*nn + zz*hreg[e];
        hreg[e] = h;
        _Float16 h16 = (_Float16)h;
        h_buf[(((size_t)d*2 + wpar)*BB + b0 + b)*HH + j0 + ej] = h16;
        if (out_mid) out_mid[((size_t)(b0+b)*TL + t)*(size_t)(2*HH) + d*HH + j0 + ej] = h16;
        else         out_fin[((size_t)(b0+b)*TL + t)*(size_t)(2*HH) + d*HH + j0 + ej] = h;
      }
    }
    __syncthreads();   // drains vmcnt(0): h_buf/out stores visible-ready before arrive
    if (tid == 0) {
      __threadfence();
      __hip_atomic_fetch_add(mycnt, 1u, __ATOMIC_RELEASE, __HIP_MEMORY_SCOPE_AGENT);
      unsigned target = 16u*(unsigned)(s + 2);
      while (__hip_atomic_load(mycnt, __ATOMIC_ACQUIRE, __HIP_MEMORY_SCOPE_AGENT) < target) {}
    }
    __syncthreads();
    __threadfence();
  }
  if (ew) {
    #pragma unroll
    for (int e = 0; e < 2; ++e) {
      int b = eb0 + e*8;
      hn_out[((size_t)(2*layer + d)*BB + b0 + b)*HH + j0 + ej] = hreg[e];
    }
  }
}

// ---------------- host launcher ----------------
extern "C" void kernel_launch(void* const* d_in, const int* in_sizes, int n_in,
                              void* d_out, int out_size, void* d_ws, size_t ws_size,
                              hipStream_t stream) {
  (void)in_sizes; (void)n_in; (void)out_size;
  const float* x   = (const float*)d_in[0];
  const float* h0  = (const float*)d_in[1];
  const float* wih = (const float*)d_in[2];
  const float* whh = (const float*)d_in[3];
  const float* bih = (const float*)d_in[4];
  const float* bhh = (const float*)d_in[5];
  float* out = (float*)d_out;

  char* ws = (char*)d_ws;
  size_t off = 0;
  auto alloc = [&](size_t bytes) {
    char* p = ws + off;
    off += (bytes + 255) & ~(size_t)255;
    return p;
  };
  _Float16* x16   = (_Float16*)alloc((size_t)BT_*II*2);          // 128 MB
  _Float16* mid16 = (_Float16*)alloc((size_t)BT_*II*2);          // 128 MB
  _Float16* gi16  = (_Float16*)alloc((size_t)2*BT_*G3_*2);       // 384 MB
  _Float16* wih16 = (_Float16*)alloc((size_t)NL*N2_*II*2);       // 12 MB
  _Float16* whh16 = (_Float16*)alloc((size_t)NL*N2_*HH*2);       // 6 MB
  _Float16* hbuf  = (_Float16*)alloc((size_t)2*2*BB*HH*2);       // 256 KB
  unsigned* cnt   = (unsigned*)alloc((size_t)16*32*4);           // 2 KB
  if (off > ws_size) {
    fprintf(stderr, "kernel_launch: workspace too small: need %zu have %zu\n", off, ws_size);
    return;
  }

  hipMemsetAsync(cnt, 0, (size_t)16*32*4, stream);
  cvt_f2h<<<2048, 256, 0, stream>>>(x,   x16,   (size_t)BT_*II/4);
  cvt_f2h<<<512,  256, 0, stream>>>(wih, wih16, (size_t)NL*N2_*II/4);
  cvt_f2h<<<512,  256, 0, stream>>>(whh, whh16, (size_t)NL*N2_*HH/4);

  float* hn = out + (size_t)BT_*II;   // h_n region: (4,64,512) after (B,T,2H)

  // layer 0
  gemm_gi<<<dim3(24, 512), 256, 0, stream>>>(x16, wih16, bih, gi16);
  gru_layer<<<128, 384, 0, stream>>>(gi16, whh16, bhh, h0, hbuf, cnt,
                                     mid16, nullptr, hn, 0);
  // layer 1
  gemm_gi<<<dim3(24, 512), 256, 0, stream>>>(mid16, wih16 + (size_t)N2_*II, bih + N2_, gi16);
  gru_layer<<<128, 384, 0, stream>>>(gi16, whh16 + (size_t)N2_*HH, bhh + N2_, h0, hbuf, cnt + 8*32,
                                     nullptr, out, hn, 1);
}

// Round 3
// 8700.702 us; speedup vs baseline: 4.2882x; 4.2882x over previous
//
#include <hip/hip_runtime.h>
#include <stdint.h>
#include <stdio.h>

// Problem constants
#define TL 1024          // T
#define BB 64            // B
#define HH 512           // H
#define II 1024          // input size (== 2H for layer 2)
#define NL 2             // layers
#define BT_ (BB*TL)      // 65536
#define G3_ 1536         // 3H
#define N2_ 3072         // 2*3H (both dirs stacked)

typedef _Float16 h8 __attribute__((ext_vector_type(8)));
typedef _Float16 h4 __attribute__((ext_vector_type(4)));
typedef _Float16 h2 __attribute__((ext_vector_type(2)));
typedef float    f4 __attribute__((ext_vector_type(4)));
typedef unsigned int u4 __attribute__((ext_vector_type(4)));

// ---------------- fp32 -> fp16 convert ----------------
__global__ void cvt_f2h(const float* __restrict__ src, _Float16* __restrict__ dst, size_t n4) {
  size_t i = (size_t)blockIdx.x*blockDim.x + threadIdx.x;
  size_t stride = (size_t)gridDim.x*blockDim.x;
  for (; i < n4; i += stride) {
    f4 v = ((const f4*)src)[i];
    h4 o;
    o[0] = (_Float16)v[0]; o[1] = (_Float16)v[1];
    o[2] = (_Float16)v[2]; o[3] = (_Float16)v[3];
    ((h4*)dst)[i] = o;
  }
}

// ---------------- gi GEMM:  C[m,n] = sum_k A[m,k]*W[n,k] + bias[n] ----------------
// A: (65536 x 1024) fp16 row-major.  W: (3072 x 1024) fp16 row-major (both dirs stacked).
// Output gi layout: [dir][m][1536] fp16, m = b*T + t.
#define LDA 40   // padded LDS stride (halves)
__launch_bounds__(256)
__global__ void gemm_gi(const _Float16* __restrict__ A, const _Float16* __restrict__ Bw,
                        const float* __restrict__ bias, _Float16* __restrict__ gi)
{
  const int bn = blockIdx.x, bm = blockIdx.y;
  const int tid = threadIdx.x;
  const int wave = tid >> 6, lane = tid & 63;
  const int wm = wave >> 1, wn = wave & 1;     // 2x2 waves -> 64x64 each
  const int lo = lane & 15, hi = lane >> 4;
  __shared__ _Float16 As[128*LDA];
  __shared__ _Float16 Bs[128*LDA];
  f4 acc[4][4] = {};
  const int r0 = tid >> 2, c0 = (tid & 3)*8;
  const _Float16* Ag = A + (size_t)(bm*128)*II;
  const _Float16* Bg = Bw + (size_t)(bn*128)*II;
  u4 a0 = *(const u4*)(Ag + (size_t)r0*II + c0);
  u4 a1 = *(const u4*)(Ag + (size_t)(64+r0)*II + c0);
  u4 b0 = *(const u4*)(Bg + (size_t)r0*II + c0);
  u4 b1 = *(const u4*)(Bg + (size_t)(64+r0)*II + c0);
  for (int kt = 0; kt < 32; ++kt) {
    __syncthreads();
    *(u4*)&As[r0*LDA + c0] = a0;
    *(u4*)&As[(64+r0)*LDA + c0] = a1;
    *(u4*)&Bs[r0*LDA + c0] = b0;
    *(u4*)&Bs[(64+r0)*LDA + c0] = b1;
    if (kt+1 < 32) {
      const int off = (kt+1)*32 + c0;
      a0 = *(const u4*)(Ag + (size_t)r0*II + off);
      a1 = *(const u4*)(Ag + (size_t)(64+r0)*II + off);
      b0 = *(const u4*)(Bg + (size_t)r0*II + off);
      b1 = *(const u4*)(Bg + (size_t)(64+r0)*II + off);
    }
    __syncthreads();
    h8 af[4], bf[4];
    #pragma unroll
    for (int i = 0; i < 4; ++i)
      af[i] = *(const h8*)&As[(wm*64 + i*16 + lo)*LDA + hi*8];
    #pragma unroll
    for (int j = 0; j < 4; ++j)
      bf[j] = *(const h8*)&Bs[(wn*64 + j*16 + lo)*LDA + hi*8];
    #pragma unroll
    for (int i = 0; i < 4; ++i)
      #pragma unroll
      for (int j = 0; j < 4; ++j)
        acc[i][j] = __builtin_amdgcn_mfma_f32_16x16x32_f16(af[i], bf[j], acc[i][j], 0, 0, 0);
  }
  const int nbase = bn*128 + wn*64;
  const int mbase = bm*128 + wm*64;
  #pragma unroll
  for (int j = 0; j < 4; ++j) {
    int n = nbase + j*16 + lo;
    int dir = (n >= G3_) ? 1 : 0;
    int row = n - dir*G3_;
    float bs = bias[n];
    #pragma unroll
    for (int i = 0; i < 4; ++i) {
      int m0 = mbase + i*16 + hi*4;
      #pragma unroll
      for (int v = 0; v < 4; ++v)
        gi[((size_t)dir*BT_ + (size_t)(m0+v))*G3_ + row] = (_Float16)(acc[i][j][v] + bs);
    }
  }
}

// ---------------- persistent GRU layer kernel ----------------
// 128 blocks. gg = bid&7: d = gg&1, g = gg>>1 (batch-group of 16). member = bid>>3
// owns j-slice [member*32,+32), all 3 gates (96 W_hh rows resident in LDS).
// ALL cross-block traffic is relaxed agent-scope atomics (sc0 sc1 -> coherence
// point, NO cache-maintenance fences). Flag ordering: returning atomic-exchange
// data stores drained by the waitcnt before s_barrier, then relaxed fetch_add.
#define LDW 520
__launch_bounds__(384, 1)
__global__ void gru_layer(const _Float16* __restrict__ gi,     // [dir][b*T+t][1536]
                          const _Float16* __restrict__ whh,    // layer: [dir][1536][512]
                          const float* __restrict__ bhh,       // layer: [dir][1536]
                          const float* __restrict__ h0,        // [4][64][512]
                          _Float16* __restrict__ h_buf,        // [dir][2][64][512]
                          unsigned* __restrict__ cnt,          // 8 counters, stride 32 uints
                          _Float16* __restrict__ out_mid,      // layer0: [b][t][1024] fp16
                          float* __restrict__ out_fin,         // layer1: [b][t][1024] fp32
                          float* __restrict__ hn_out,          // [4][64][512] fp32
                          int layer)
{
  const int bid = blockIdx.x;
  const int gg = bid & 7, d = gg & 1, g = gg >> 1;
  const int member = bid >> 3;
  const int j0 = member * 32, b0 = g * 16;
  const int tid = threadIdx.x;
  const int wave = tid >> 6, lane = tid & 63, lo = lane & 15, hi = lane >> 4;
  const int gate = wave >> 1, jh = wave & 1;     // 6 waves: 3 gates x 2 j-halves

  __shared__ _Float16 wlds[3][32][LDW];
  __shared__ _Float16 hlds[16][LDW];
  __shared__ float    ghlds[3][32][17];

  // --- load resident W_hh slice: rows gate*512 + j0 + jj ---
  const _Float16* wsrc = whh + (size_t)d*G3_*HH;
  #pragma unroll
  for (int it = 0; it < 16; ++it) {
    int idx = it*384 + tid;            // 6144 chunks of 8 halves (96 rows x 64 chunks)
    int row = idx >> 6;
    int c8 = (idx & 63) * 8;
    int gt = row >> 5, jj = row & 31;
    u4 v = *(const u4*)(wsrc + (size_t)(gt*HH + j0 + jj)*HH + c8);
    *(u4*)&wlds[gt][jj][c8] = v;
  }

  unsigned* mycnt = cnt + gg*32;       // 128B spacing between group counters
  const int ejp = tid & 15;            // j-pair index within slice (j = j0 + 2*ejp)
  const int eb  = tid >> 4;            // 0..15: batch within chunk (ew threads)
  const bool ew = (tid < 256);
  const int ejA = j0 + 2*ejp;

  float hj[2];
  float bhr[2], bhz[2], bhn[2];

  if (ew) {
    #pragma unroll
    for (int u = 0; u < 2; ++u) {
      bhr[u] = bhh[(size_t)d*G3_ + 0*HH + ejA + u];
      bhz[u] = bhh[(size_t)d*G3_ + 1*HH + ejA + u];
      bhn[u] = bhh[(size_t)d*G3_ + 2*HH + ejA + u];
      hj[u]  = h0[((size_t)(2*layer + d)*BB + b0 + eb)*HH + ejA + u];
    }
    h2 p; p[0] = (_Float16)hj[0]; p[1] = (_Float16)hj[1];
    unsigned pu = __builtin_bit_cast(unsigned, p);
    unsigned old = __hip_atomic_exchange(
        (unsigned*)(h_buf + (((size_t)d*2 + 0)*BB + b0 + eb)*HH + ejA),
        pu, __ATOMIC_RELAXED, __HIP_MEMORY_SCOPE_AGENT);
    asm volatile("" :: "v"(old));      // keep returning form: vmcnt retire == LLC ack
  }
  asm volatile("s_waitcnt vmcnt(0)" ::: "memory");
  __syncthreads();
  if (tid == 0)
    __hip_atomic_fetch_add(mycnt, 1u, __ATOMIC_RELAXED, __HIP_MEMORY_SCOPE_AGENT);

  for (int s = 0; s < TL; ++s) {
    const int t = d ? (TL-1 - s) : s;
    const int rpar = s & 1, wpar = rpar ^ 1;
    unsigned giR = 0, giZ = 0, giN = 0;
    if (ew) {
      // issue early: latency hides under poll + exchange phases
      const _Float16* p = gi + ((size_t)d*BT_ + (size_t)(b0 + eb)*TL + t)*(size_t)G3_ + ejA;
      giR = *(const unsigned*)(p);
      giZ = *(const unsigned*)(p + HH);
      giN = *(const unsigned*)(p + 2*HH);
    }
    if (tid == 0) {
      unsigned target = 16u*(unsigned)(s + 1);
      while (__hip_atomic_load(mycnt, __ATOMIC_RELAXED, __HIP_MEMORY_SCOPE_AGENT) < target) {}
    }
    __syncthreads();
    // --- fetch h(s) for our batch chunk (written by all 16 members) -> LDS ---
    {
      const uint64_t* src = (const uint64_t*)(h_buf + (((size_t)d*2 + rpar)*BB + b0)*HH);
      #pragma unroll
      for (int it = 0; it < 6; ++it) {
        int idx = it*384 + tid;                  // 2048 x 8B = 16 KB
        if (idx < 2048) {
          int b = idx >> 7, jq = idx & 127;      // per-batch stride = 512 halves = 128 u64
          uint64_t v = __hip_atomic_load(src + (size_t)b*128 + jq,
                                         __ATOMIC_RELAXED, __HIP_MEMORY_SCOPE_AGENT);
          *(uint64_t*)&hlds[b][jq*4] = v;
        }
      }
    }
    __syncthreads();
    // --- gh slice: (16b x 16j) per wave over K=512 ---
    f4 acc = {0.f, 0.f, 0.f, 0.f};
    #pragma unroll
    for (int kk = 0; kk < 16; ++kk) {
      h8 af = *(const h8*)&hlds[lo][kk*32 + hi*8];
      h8 bf = *(const h8*)&wlds[gate][jh*16 + lo][kk*32 + hi*8];
      acc = __builtin_amdgcn_mfma_f32_16x16x32_f16(af, bf, acc, 0, 0, 0);
    }
    #pragma unroll
    for (int v = 0; v < 4; ++v)
      ghlds[gate][jh*16 + lo][hi*4 + v] = acc[v];   // [gate][j][b]
    __syncthreads();
    // --- elementwise GRU update (2 consecutive j, 1 batch per thread) ---
    if (ew) {
      h2 pR = __builtin_bit_cast(h2, giR);
      h2 pZ = __builtin_bit_cast(h2, giZ);
      h2 pN = __builtin_bit_cast(h2, giN);
      h2 hnew;
      float hv[2];
      #pragma unroll
      for (int u = 0; u < 2; ++u) {
        float ir = (float)pR[u], iz = (float)pZ[u], inn = (float)pN[u];
        float hr = ghlds[0][2*ejp+u][eb] + bhr[u];
        float hz = ghlds[1][2*ejp+u][eb] + bhz[u];
        float hn = ghlds[2][2*ejp+u][eb] + bhn[u];
        float rr = 1.f/(1.f + __expf(-(ir + hr)));
        float zz = 1.f/(1.f + __expf(-(iz + hz)));
        float xx = inn + rr*hn;
        float nn = 1.f - 2.f/(__expf(2.f*xx) + 1.f);   // tanh, overflow-safe both ends
        float h  = (1.f - zz)*nn + zz*hj[u];
        hj[u] = h;
        hnew[u] = (_Float16)h;
        hv[u] = h;
      }
      unsigned hu = __builtin_bit_cast(unsigned, hnew);
      unsigned old = __hip_atomic_exchange(
          (unsigned*)(h_buf + (((size_t)d*2 + wpar)*BB + b0 + eb)*HH + ejA),
          hu, __ATOMIC_RELAXED, __HIP_MEMORY_SCOPE_AGENT);
      asm volatile("" :: "v"(old));
      if (out_mid) {
        *(unsigned*)(out_mid + ((size_t)(b0+eb)*TL + t)*(size_t)(2*HH) + d*HH + ejA) = hu;
      } else {
        out_fin[((size_t)(b0+eb)*TL + t)*(size_t)(2*HH) + d*HH + ejA]     = hv[0];
        out_fin[((size_t)(b0+eb)*TL + t)*(size_t)(2*HH) + d*HH + ejA + 1] = hv[1];
      }
    }
    asm volatile("s_waitcnt vmcnt(0)" ::: "memory");
    __syncthreads();   // all waves' exchanges acked at LLC before arrive
    if (tid == 0)
      __hip_atomic_fetch_add(mycnt, 1u, __ATOMIC_RELAXED, __HIP_MEMORY_SCOPE_AGENT);
  }
  if (ew) {
    #pragma unroll
    for (int u = 0; u < 2; ++u)
      hn_out[((size_t)(2*layer + d)*BB + b0 + eb)*HH + ejA + u] = hj[u];
  }
}

// ---------------- host launcher ----------------
extern "C" void kernel_launch(void* const* d_in, const int* in_sizes, int n_in,
                              void* d_out, int out_size, void* d_ws, size_t ws_size,
                              hipStream_t stream) {
  (void)in_sizes; (void)n_in; (void)out_size;
  const float* x   = (const float*)d_in[0];
  const float* h0  = (const float*)d_in[1];
  const float* wih = (const float*)d_in[2];
  const float* whh = (const float*)d_in[3];
  const float* bih = (const float*)d_in[4];
  const float* bhh = (const float*)d_in[5];
  float* out = (float*)d_out;

  char* ws = (char*)d_ws;
  size_t off = 0;
  auto alloc = [&](size_t bytes) {
    char* p = ws + off;
    off += (bytes + 255) & ~(size_t)255;
    return p;
  };
  _Float16* x16   = (_Float16*)alloc((size_t)BT_*II*2);          // 128 MB
  _Float16* mid16 = (_Float16*)alloc((size_t)BT_*II*2);          // 128 MB
  _Float16* gi16  = (_Float16*)alloc((size_t)2*BT_*G3_*2);       // 384 MB
  _Float16* wih16 = (_Float16*)alloc((size_t)NL*N2_*II*2);       // 12 MB
  _Float16* whh16 = (_Float16*)alloc((size_t)NL*N2_*HH*2);       // 6 MB
  _Float16* hbuf  = (_Float16*)alloc((size_t)2*2*BB*HH*2);       // 256 KB
  unsigned* cnt   = (unsigned*)alloc((size_t)16*32*4);           // 2 KB
  if (off > ws_size) {
    fprintf(stderr, "kernel_launch: workspace too small: need %zu have %zu\n", off, ws_size);
    return;
  }

  hipMemsetAsync(cnt, 0, (size_t)16*32*4, stream);
  cvt_f2h<<<2048, 256, 0, stream>>>(x,   x16,   (size_t)BT_*II/4);
  cvt_f2h<<<512,  256, 0, stream>>>(wih, wih16, (size_t)NL*N2_*II/4);
  cvt_f2h<<<512,  256, 0, stream>>>(whh, whh16, (size_t)NL*N2_*HH/4);

  float* hn = out + (size_t)BT_*II;   // h_n region: (4,64,512) after (B,T,2H)

  // layer 0
  gemm_gi<<<dim3(24, 512), 256, 0, stream>>>(x16, wih16, bih, gi16);
  gru_layer<<<128, 384, 0, stream>>>(gi16, whh16, bhh, h0, hbuf, cnt,
                                     mid16, nullptr, hn, 0);
  // layer 1
  gemm_gi<<<dim3(24, 512), 256, 0, stream>>>(mid16, wih16 + (size_t)N2_*II, bih + N2_, gi16);
  gru_layer<<<128, 384, 0, stream>>>(gi16, whh16 + (size_t)N2_*HH, bhh + N2_, h0, hbuf, cnt + 8*32,
                                     nullptr, out, hn, 1);
}

// Round 6
// 8284.498 us; speedup vs baseline: 4.5037x; 1.0502x over previous
//
#include <hip/hip_runtime.h>
#include <stdint.h>
#include <stdio.h>

// Problem constants
#define TL 1024          // T
#define BB 64            // B
#define HH 512           // H
#define II 1024          // input size (== 2H for layer 2)
#define NL 2             // layers
#define BT_ (BB*TL)      // 65536
#define G3_ 1536         // 3H
#define N2_ 3072         // 2*3H (both dirs stacked)

typedef _Float16 h8 __attribute__((ext_vector_type(8)));
typedef _Float16 h4 __attribute__((ext_vector_type(4)));
typedef _Float16 h2 __attribute__((ext_vector_type(2)));
typedef float    f4 __attribute__((ext_vector_type(4)));
typedef unsigned int u4 __attribute__((ext_vector_type(4)));
typedef unsigned int u2v __attribute__((ext_vector_type(2)));

// ---------------- fp32 -> fp16 convert ----------------
__global__ void cvt_f2h(const float* __restrict__ src, _Float16* __restrict__ dst, size_t n4) {
  size_t i = (size_t)blockIdx.x*blockDim.x + threadIdx.x;
  size_t stride = (size_t)gridDim.x*blockDim.x;
  for (; i < n4; i += stride) {
    f4 v = ((const f4*)src)[i];
    h4 o;
    o[0] = (_Float16)v[0]; o[1] = (_Float16)v[1];
    o[2] = (_Float16)v[2]; o[3] = (_Float16)v[3];
    ((h4*)dst)[i] = o;
  }
}

// ---------------- gi GEMM (unchanged, proven) ----------------
#define LDA 40
__launch_bounds__(256)
__global__ void gemm_gi(const _Float16* __restrict__ A, const _Float16* __restrict__ Bw,
                        const float* __restrict__ bias, _Float16* __restrict__ gi)
{
  const int bn = blockIdx.x, bm = blockIdx.y;
  const int tid = threadIdx.x;
  const int wave = tid >> 6, lane = tid & 63;
  const int wm = wave >> 1, wn = wave & 1;
  const int lo = lane & 15, hi = lane >> 4;
  __shared__ _Float16 As[128*LDA];
  __shared__ _Float16 Bs[128*LDA];
  f4 acc[4][4] = {};
  const int r0 = tid >> 2, c0 = (tid & 3)*8;
  const _Float16* Ag = A + (size_t)(bm*128)*II;
  const _Float16* Bg = Bw + (size_t)(bn*128)*II;
  u4 a0 = *(const u4*)(Ag + (size_t)r0*II + c0);
  u4 a1 = *(const u4*)(Ag + (size_t)(64+r0)*II + c0);
  u4 b0 = *(const u4*)(Bg + (size_t)r0*II + c0);
  u4 b1 = *(const u4*)(Bg + (size_t)(64+r0)*II + c0);
  for (int kt = 0; kt < 32; ++kt) {
    __syncthreads();
    *(u4*)&As[r0*LDA + c0] = a0;
    *(u4*)&As[(64+r0)*LDA + c0] = a1;
    *(u4*)&Bs[r0*LDA + c0] = b0;
    *(u4*)&Bs[(64+r0)*LDA + c0] = b1;
    if (kt+1 < 32) {
      const int off = (kt+1)*32 + c0;
      a0 = *(const u4*)(Ag + (size_t)r0*II + off);
      a1 = *(const u4*)(Ag + (size_t)(64+r0)*II + off);
      b0 = *(const u4*)(Bg + (size_t)r0*II + off);
      b1 = *(const u4*)(Bg + (size_t)(64+r0)*II + off);
    }
    __syncthreads();
    h8 af[4], bf[4];
    #pragma unroll
    for (int i = 0; i < 4; ++i)
      af[i] = *(const h8*)&As[(wm*64 + i*16 + lo)*LDA + hi*8];
    #pragma unroll
    for (int j = 0; j < 4; ++j)
      bf[j] = *(const h8*)&Bs[(wn*64 + j*16 + lo)*LDA + hi*8];
    #pragma unroll
    for (int i = 0; i < 4; ++i)
      #pragma unroll
      for (int j = 0; j < 4; ++j)
        acc[i][j] = __builtin_amdgcn_mfma_f32_16x16x32_f16(af[i], bf[j], acc[i][j], 0, 0, 0);
  }
  const int nbase = bn*128 + wn*64;
  const int mbase = bm*128 + wm*64;
  #pragma unroll
  for (int j = 0; j < 4; ++j) {
    int n = nbase + j*16 + lo;
    int dir = (n >= G3_) ? 1 : 0;
    int row = n - dir*G3_;
    float bs = bias[n];
    #pragma unroll
    for (int i = 0; i < 4; ++i) {
      int m0 = mbase + i*16 + hi*4;
      #pragma unroll
      for (int v = 0; v < 4; ++v)
        gi[((size_t)dir*BT_ + (size_t)(m0+v))*G3_ + row] = (_Float16)(acc[i][j][v] + bs);
    }
  }
}

// ---------------- persistent GRU layer kernel (tagged-mailbox, ATOMIC 8B entries) ----------------
// 128 blocks. gg=bid&7: d=gg&1, g=gg>>1 (batch-chunk of 16). member=bid>>3 owns
// j-slice [member*32,+32), all 3 gates resident in LDS (96 rows W_hh).
// h exchange: 8B entries {h2 pair | tag<<32}, EVERY access a relaxed agent-scope
// 8B atomic (single-copy atomic - R5's torn non-atomic dwordx2/x4 was the bug).
//   read step s : parity s&1,  expect tag >= s+1   (h version s; h0 tagged 1)
//   write end s : parity (s+1)&1, tag s+2, fire-and-forget (no ack, no flags, no RMW)
// 2-step back-pressure (writer overwriting version s needs all readers' end-of-(s+1)
// tags, which follow their version-s reads). Worst case = retries, never deadlock.
#define LDW 520
__launch_bounds__(384, 1)
__global__ void gru_layer(const _Float16* __restrict__ gi,     // [dir][b*T+t][1536]
                          const _Float16* __restrict__ whh,    // layer: [dir][1536][512]
                          const float* __restrict__ bhh,       // layer: [dir][1536]
                          const float* __restrict__ h0,        // [4][64][512]
                          unsigned long long* __restrict__ tagh, // layer: [d][par][64][256] u64
                          _Float16* __restrict__ out_mid,      // layer0: [b][t][1024] fp16
                          float* __restrict__ out_fin,         // layer1: [b][t][1024] fp32
                          float* __restrict__ hn_out,          // [4][64][512] fp32
                          int layer)
{
  const int bid = blockIdx.x;
  const int gg = bid & 7, d = gg & 1, g = gg >> 1;
  const int member = bid >> 3;
  const int j0 = member * 32, b0 = g * 16;
  const int tid = threadIdx.x;
  const int wave = tid >> 6, lane = tid & 63, lo = lane & 15, hi = lane >> 4;
  const int gate = wave >> 1, jh = wave & 1;     // 6 waves: 3 gates x 2 j-halves

  __shared__ _Float16 wlds[3][32][LDW];
  __shared__ _Float16 hlds[16][LDW];
  __shared__ float    ghlds[3][32][17];
  __shared__ unsigned wok[8];

  // --- load resident W_hh slice ---
  const _Float16* wsrc = whh + (size_t)d*G3_*HH;
  #pragma unroll
  for (int it = 0; it < 16; ++it) {
    int idx = it*384 + tid;
    int row = idx >> 6;
    int c8 = (idx & 63) * 8;
    int gt = row >> 5, jj = row & 31;
    u4 v = *(const u4*)(wsrc + (size_t)(gt*HH + j0 + jj)*HH + c8);
    *(u4*)&wlds[gt][jj][c8] = v;
  }

  const int ejp = tid & 15;              // j-pair within slice
  const int eb  = tid >> 4;              // 0..15 batch within chunk (ew threads)
  const bool ew = (tid < 256);
  const int ejA = j0 + 2*ejp;

  unsigned long long* Tb = tagh + (size_t)d*2*BB*256;   // this direction's 2 parities

  float hj[2];
  float bhr[2], bhz[2], bhn[2];

  if (ew) {
    #pragma unroll
    for (int u = 0; u < 2; ++u) {
      bhr[u] = bhh[(size_t)d*G3_ + 0*HH + ejA + u];
      bhz[u] = bhh[(size_t)d*G3_ + 1*HH + ejA + u];
      bhn[u] = bhh[(size_t)d*G3_ + 2*HH + ejA + u];
      hj[u]  = h0[((size_t)(2*layer + d)*BB + b0 + eb)*HH + ejA + u];
    }
    h2 p; p[0] = (_Float16)hj[0]; p[1] = (_Float16)hj[1];
    unsigned long long ent = (unsigned long long)__builtin_bit_cast(unsigned, p) | (1ull << 32);
    unsigned long long* ptr = Tb + (size_t)0*BB*256 + (size_t)(b0 + eb)*256 + (member*16 + ejp);
    __hip_atomic_store(ptr, ent, __ATOMIC_RELAXED, __HIP_MEMORY_SCOPE_AGENT);
  }
  __syncthreads();   // wlds ready

  for (int s = 0; s < TL; ++s) {
    const int t = d ? (TL-1 - s) : s;
    const int rpar = s & 1, wpar = rpar ^ 1;
    const unsigned tgt = (unsigned)(s + 1);
    unsigned giR = 0, giZ = 0, giN = 0;
    if (ew) {   // issue early; consumed after barB, latency hidden under poll+MFMA
      const _Float16* p = gi + ((size_t)d*BT_ + (size_t)(b0 + eb)*TL + t)*(size_t)G3_ + ejA;
      giR = *(const unsigned*)(p);
      giZ = *(const unsigned*)(p + HH);
      giN = *(const unsigned*)(p + 2*HH);
    }
    // --- poll + cooperative tagged load of h(s) -> LDS (8B atomic entries) ---
    {
      const unsigned long long* Trd = Tb + (size_t)rpar*BB*256;
      for (;;) {
        unsigned long long E0[6], E1[6];
        #pragma unroll
        for (int it = 0; it < 6; ++it) {
          int idx = it*384 + tid;                    // 2048 pair-tasks (2 entries each)
          if (idx < 2048) {
            const unsigned long long* pa = Trd + (size_t)(b0 + (idx >> 7))*256 + (idx & 127)*2;
            E0[it] = __hip_atomic_load(pa,     __ATOMIC_RELAXED, __HIP_MEMORY_SCOPE_AGENT);
            E1[it] = __hip_atomic_load(pa + 1, __ATOMIC_RELAXED, __HIP_MEMORY_SCOPE_AGENT);
          }
        }
        unsigned okm = 1u;
        #pragma unroll
        for (int it = 0; it < 6; ++it) {
          int idx = it*384 + tid;
          if (idx < 2048) {
            okm &= (unsigned)((E0[it] >> 32) >= tgt) & (unsigned)((E1[it] >> 32) >= tgt);
            int b = idx >> 7, j4 = (idx & 127)*4;
            u2v dv; dv[0] = (unsigned)E0[it]; dv[1] = (unsigned)E1[it];
            *(u2v*)&hlds[b][j4] = dv;
          }
        }
        unsigned long long bal = __ballot(okm != 0u);
        if (lane == 0) wok[wave] = (bal == ~0ull) ? 1u : 0u;
        __syncthreads();                               // also publishes hlds on success
        unsigned allok = wok[0] & wok[1] & wok[2] & wok[3] & wok[4] & wok[5];
        if (allok) break;
        __syncthreads();                               // WAR on wok before retry
      }
    }
    // --- gh slice: (16b x 16j) per wave over K=512 ---
    f4 acc = {0.f, 0.f, 0.f, 0.f};
    #pragma unroll
    for (int kk = 0; kk < 16; ++kk) {
      h8 af = *(const h8*)&hlds[lo][kk*32 + hi*8];
      h8 bf = *(const h8*)&wlds[gate][jh*16 + lo][kk*32 + hi*8];
      acc = __builtin_amdgcn_mfma_f32_16x16x32_f16(af, bf, acc, 0, 0, 0);
    }
    #pragma unroll
    for (int v = 0; v < 4; ++v)
      ghlds[gate][jh*16 + lo][hi*4 + v] = acc[v];   // [gate][j][b]
    __syncthreads();   // barB: ghlds RAW
    // --- elementwise GRU update + tagged h publish (fire-and-forget atomic) ---
    if (ew) {
      h2 pR = __builtin_bit_cast(h2, giR);
      h2 pZ = __builtin_bit_cast(h2, giZ);
      h2 pN = __builtin_bit_cast(h2, giN);
      h2 hnew; float hv[2];
      #pragma unroll
      for (int u = 0; u < 2; ++u) {
        float ir = (float)pR[u], iz = (float)pZ[u], inn = (float)pN[u];
        float hr = ghlds[0][2*ejp+u][eb] + bhr[u];
        float hz = ghlds[1][2*ejp+u][eb] + bhz[u];
        float hn = ghlds[2][2*ejp+u][eb] + bhn[u];
        float rr = 1.f/(1.f + __expf(-(ir + hr)));
        float zz = 1.f/(1.f + __expf(-(iz + hz)));
        float xx = inn + rr*hn;
        float nn = 1.f - 2.f/(__expf(2.f*xx) + 1.f);   // tanh, overflow-safe
        float h  = (1.f - zz)*nn + zz*hj[u];
        hj[u] = h; hnew[u] = (_Float16)h; hv[u] = h;
      }
      unsigned hu = __builtin_bit_cast(unsigned, hnew);
      unsigned long long ent = (unsigned long long)hu | ((unsigned long long)(s + 2) << 32);
      unsigned long long* ptr = Tb + (size_t)wpar*BB*256 + (size_t)(b0 + eb)*256 + (member*16 + ejp);
      __hip_atomic_store(ptr, ent, __ATOMIC_RELAXED, __HIP_MEMORY_SCOPE_AGENT);
      if (out_mid) {
        *(unsigned*)(out_mid + ((size_t)(b0+eb)*TL + t)*(size_t)(2*HH) + d*HH + ejA) = hu;
      } else {
        u2v ov; ov[0] = __builtin_bit_cast(unsigned, hv[0]); ov[1] = __builtin_bit_cast(unsigned, hv[1]);
        *(u2v*)(out_fin + ((size_t)(b0+eb)*TL + t)*(size_t)(2*HH) + d*HH + ejA) = ov;
      }
    }
    // no end barrier: next step's poll barrier provides all needed separation
  }
  if (ew) {
    #pragma unroll
    for (int u = 0; u < 2; ++u)
      hn_out[((size_t)(2*layer + d)*BB + b0 + eb)*HH + ejA + u] = hj[u];
  }
}

// ---------------- host launcher ----------------
extern "C" void kernel_launch(void* const* d_in, const int* in_sizes, int n_in,
                              void* d_out, int out_size, void* d_ws, size_t ws_size,
                              hipStream_t stream) {
  (void)in_sizes; (void)n_in; (void)out_size;
  const float* x   = (const float*)d_in[0];
  const float* h0  = (const float*)d_in[1];
  const float* wih = (const float*)d_in[2];
  const float* whh = (const float*)d_in[3];
  const float* bih = (const float*)d_in[4];
  const float* bhh = (const float*)d_in[5];
  float* out = (float*)d_out;

  char* ws = (char*)d_ws;
  size_t off = 0;
  auto alloc = [&](size_t bytes) {
    char* p = ws + off;
    off += (bytes + 255) & ~(size_t)255;
    return p;
  };
  _Float16* x16   = (_Float16*)alloc((size_t)BT_*II*2);          // 128 MB
  _Float16* mid16 = (_Float16*)alloc((size_t)BT_*II*2);          // 128 MB
  _Float16* gi16  = (_Float16*)alloc((size_t)2*BT_*G3_*2);       // 384 MB
  _Float16* wih16 = (_Float16*)alloc((size_t)NL*N2_*II*2);       // 12 MB
  _Float16* whh16 = (_Float16*)alloc((size_t)NL*N2_*HH*2);       // 6 MB
  unsigned long long* tagh = (unsigned long long*)alloc((size_t)NL*2*2*BB*256*8); // 1 MB
  if (off > ws_size) {
    fprintf(stderr, "kernel_launch: workspace too small: need %zu have %zu\n", off, ws_size);
    return;
  }

  hipMemsetAsync(tagh, 0, (size_t)NL*2*2*BB*256*8, stream);      // clear stale tags (per replay)
  cvt_f2h<<<2048, 256, 0, stream>>>(x,   x16,   (size_t)BT_*II/4);
  cvt_f2h<<<512,  256, 0, stream>>>(wih, wih16, (size_t)NL*N2_*II/4);
  cvt_f2h<<<512,  256, 0, stream>>>(whh, whh16, (size_t)NL*N2_*HH/4);

  float* hn = out + (size_t)BT_*II;   // h_n region: (4,64,512) after (B,T,2H)

  // layer 0
  gemm_gi<<<dim3(24, 512), 256, 0, stream>>>(x16, wih16, bih, gi16);
  gru_layer<<<128, 384, 0, stream>>>(gi16, whh16, bhh, h0, tagh,
                                     mid16, nullptr, hn, 0);
  // layer 1
  gemm_gi<<<dim3(24, 512), 256, 0, stream>>>(mid16, wih16 + (size_t)N2_*II, bih + N2_, gi16);
  gru_layer<<<128, 384, 0, stream>>>(gi16, whh16 + (size_t)N2_*HH, bhh + N2_, h0,
                                     tagh + (size_t)2*2*BB*256, nullptr, out, hn, 1);
}

// Round 7
// 7760.745 us; speedup vs baseline: 4.8076x; 1.0675x over previous
//
#include <hip/hip_runtime.h>
#include <stdint.h>
#include <stdio.h>

// Problem constants
#define TL 1024          // T
#define BB 64            // B
#define HH 512           // H
#define II 1024          // input size (== 2H for layer 2)
#define NL 2             // layers
#define BT_ (BB*TL)      // 65536
#define G3_ 1536         // 3H
#define N2_ 3072         // 2*3H (both dirs stacked)

typedef _Float16 h8 __attribute__((ext_vector_type(8)));
typedef _Float16 h4 __attribute__((ext_vector_type(4)));
typedef _Float16 h2 __attribute__((ext_vector_type(2)));
typedef float    f4 __attribute__((ext_vector_type(4)));
typedef unsigned int u4 __attribute__((ext_vector_type(4)));
typedef unsigned int u2v __attribute__((ext_vector_type(2)));

// ---------------- fp32 -> fp16 convert ----------------
__global__ void cvt_f2h(const float* __restrict__ src, _Float16* __restrict__ dst, size_t n4) {
  size_t i = (size_t)blockIdx.x*blockDim.x + threadIdx.x;
  size_t stride = (size_t)gridDim.x*blockDim.x;
  for (; i < n4; i += stride) {
    f4 v = ((const f4*)src)[i];
    h4 o;
    o[0] = (_Float16)v[0]; o[1] = (_Float16)v[1];
    o[2] = (_Float16)v[2]; o[3] = (_Float16)v[3];
    ((h4*)dst)[i] = o;
  }
}

// ---------------- gi GEMM (unchanged, proven) ----------------
#define LDA 40
__launch_bounds__(256)
__global__ void gemm_gi(const _Float16* __restrict__ A, const _Float16* __restrict__ Bw,
                        const float* __restrict__ bias, _Float16* __restrict__ gi)
{
  const int bn = blockIdx.x, bm = blockIdx.y;
  const int tid = threadIdx.x;
  const int wave = tid >> 6, lane = tid & 63;
  const int wm = wave >> 1, wn = wave & 1;
  const int lo = lane & 15, hi = lane >> 4;
  __shared__ _Float16 As[128*LDA];
  __shared__ _Float16 Bs[128*LDA];
  f4 acc[4][4] = {};
  const int r0 = tid >> 2, c0 = (tid & 3)*8;
  const _Float16* Ag = A + (size_t)(bm*128)*II;
  const _Float16* Bg = Bw + (size_t)(bn*128)*II;
  u4 a0 = *(const u4*)(Ag + (size_t)r0*II + c0);
  u4 a1 = *(const u4*)(Ag + (size_t)(64+r0)*II + c0);
  u4 b0 = *(const u4*)(Bg + (size_t)r0*II + c0);
  u4 b1 = *(const u4*)(Bg + (size_t)(64+r0)*II + c0);
  for (int kt = 0; kt < 32; ++kt) {
    __syncthreads();
    *(u4*)&As[r0*LDA + c0] = a0;
    *(u4*)&As[(64+r0)*LDA + c0] = a1;
    *(u4*)&Bs[r0*LDA + c0] = b0;
    *(u4*)&Bs[(64+r0)*LDA + c0] = b1;
    if (kt+1 < 32) {
      const int off = (kt+1)*32 + c0;
      a0 = *(const u4*)(Ag + (size_t)r0*II + off);
      a1 = *(const u4*)(Ag + (size_t)(64+r0)*II + off);
      b0 = *(const u4*)(Bg + (size_t)r0*II + off);
      b1 = *(const u4*)(Bg + (size_t)(64+r0)*II + off);
    }
    __syncthreads();
    h8 af[4], bf[4];
    #pragma unroll
    for (int i = 0; i < 4; ++i)
      af[i] = *(const h8*)&As[(wm*64 + i*16 + lo)*LDA + hi*8];
    #pragma unroll
    for (int j = 0; j < 4; ++j)
      bf[j] = *(const h8*)&Bs[(wn*64 + j*16 + lo)*LDA + hi*8];
    #pragma unroll
    for (int i = 0; i < 4; ++i)
      #pragma unroll
      for (int j = 0; j < 4; ++j)
        acc[i][j] = __builtin_amdgcn_mfma_f32_16x16x32_f16(af[i], bf[j], acc[i][j], 0, 0, 0);
  }
  const int nbase = bn*128 + wn*64;
  const int mbase = bm*128 + wm*64;
  #pragma unroll
  for (int j = 0; j < 4; ++j) {
    int n = nbase + j*16 + lo;
    int dir = (n >= G3_) ? 1 : 0;
    int row = n - dir*G3_;
    float bs = bias[n];
    #pragma unroll
    for (int i = 0; i < 4; ++i) {
      int m0 = mbase + i*16 + hi*4;
      #pragma unroll
      for (int v = 0; v < 4; ++v)
        gi[((size_t)dir*BT_ + (size_t)(m0+v))*G3_ + row] = (_Float16)(acc[i][j][v] + bs);
    }
  }
}

// ---------------- persistent GRU layer kernel (tagged-mailbox + sentinel spin) ----------------
// 128 blocks. gg=bid&7: d=gg&1, g=gg>>1 (batch-chunk of 16). member=bid>>3 owns
// j-slice [member*32,+32), all 3 gates resident in LDS (96 rows W_hh).
// h exchange: 8B entries {h2 pair | tag<<32}, relaxed agent-scope 8B atomics only
// (single-copy atomic; proven R6). read step s: parity s&1, tag>=s+1; write end s:
// parity (s+1)&1, tag s+2, fire-and-forget. 2-step back-pressure as before.
// NEW (R7): cheap per-thread sentinel spin (1 entry per (member,batch) pair, no
// barriers, no bulk traffic) gates the expensive verified 32KB read, which now
// passes on iteration 1 almost always. Verify + retry loop kept as correctness
// fallback - protocol and safety arguments unchanged from the R6-passed kernel.
#define LDW 520
__launch_bounds__(384, 1)
__global__ void gru_layer(const _Float16* __restrict__ gi,     // [dir][b*T+t][1536]
                          const _Float16* __restrict__ whh,    // layer: [dir][1536][512]
                          const float* __restrict__ bhh,       // layer: [dir][1536]
                          const float* __restrict__ h0,        // [4][64][512]
                          unsigned long long* __restrict__ tagh, // layer: [d][par][64][256] u64
                          _Float16* __restrict__ out_mid,      // layer0: [b][t][1024] fp16
                          float* __restrict__ out_fin,         // layer1: [b][t][1024] fp32
                          float* __restrict__ hn_out,          // [4][64][512] fp32
                          int layer)
{
  const int bid = blockIdx.x;
  const int gg = bid & 7, d = gg & 1, g = gg >> 1;
  const int member = bid >> 3;
  const int j0 = member * 32, b0 = g * 16;
  const int tid = threadIdx.x;
  const int wave = tid >> 6, lane = tid & 63, lo = lane & 15, hi = lane >> 4;
  const int gate = wave >> 1, jh = wave & 1;     // 6 waves: 3 gates x 2 j-halves

  __shared__ _Float16 wlds[3][32][LDW];
  __shared__ _Float16 hlds[16][LDW];
  __shared__ float    ghlds[3][32][17];
  __shared__ unsigned wok[8];

  // --- load resident W_hh slice ---
  const _Float16* wsrc = whh + (size_t)d*G3_*HH;
  #pragma unroll
  for (int it = 0; it < 16; ++it) {
    int idx = it*384 + tid;
    int row = idx >> 6;
    int c8 = (idx & 63) * 8;
    int gt = row >> 5, jj = row & 31;
    u4 v = *(const u4*)(wsrc + (size_t)(gt*HH + j0 + jj)*HH + c8);
    *(u4*)&wlds[gt][jj][c8] = v;
  }

  const int ejp = tid & 15;              // j-pair within slice
  const int eb  = tid >> 4;              // 0..15 batch within chunk (ew threads)
  const bool ew = (tid < 256);
  const int ejA = j0 + 2*ejp;

  unsigned long long* Tb = tagh + (size_t)d*2*BB*256;   // this direction's 2 parities

  float hj[2];
  float bhr[2], bhz[2], bhn[2];

  if (ew) {
    #pragma unroll
    for (int u = 0; u < 2; ++u) {
      bhr[u] = bhh[(size_t)d*G3_ + 0*HH + ejA + u];
      bhz[u] = bhh[(size_t)d*G3_ + 1*HH + ejA + u];
      bhn[u] = bhh[(size_t)d*G3_ + 2*HH + ejA + u];
      hj[u]  = h0[((size_t)(2*layer + d)*BB + b0 + eb)*HH + ejA + u];
    }
    h2 p; p[0] = (_Float16)hj[0]; p[1] = (_Float16)hj[1];
    unsigned long long ent = (unsigned long long)__builtin_bit_cast(unsigned, p) | (1ull << 32);
    unsigned long long* ptr = Tb + (size_t)0*BB*256 + (size_t)(b0 + eb)*256 + (member*16 + ejp);
    __hip_atomic_store(ptr, ent, __ATOMIC_RELAXED, __HIP_MEMORY_SCOPE_AGENT);
  }
  __syncthreads();   // wlds ready

  // sentinel for this thread (tid<256): member m = tid&15, batch b = tid>>4,
  // entry slot m*16 + (b&15)  -> covers every (member, batch) publisher group
  const int sm = tid & 15, sb = tid >> 4;
  const size_t sent_off = (size_t)(b0 + sb)*256 + sm*16 + (sb & 15);

  for (int s = 0; s < TL; ++s) {
    const int t = d ? (TL-1 - s) : s;
    const int rpar = s & 1, wpar = rpar ^ 1;
    const unsigned tgt = (unsigned)(s + 1);
    unsigned giR = 0, giZ = 0, giN = 0;
    if (ew) {   // issue early; latency hides under sentinel spin
      const _Float16* p = gi + ((size_t)d*BT_ + (size_t)(b0 + eb)*TL + t)*(size_t)G3_ + ejA;
      giR = *(const unsigned*)(p);
      giZ = *(const unsigned*)(p + HH);
      giN = *(const unsigned*)(p + 2*HH);
    }
    const unsigned long long* Trd = Tb + (size_t)rpar*BB*256;
    // --- cheap sentinel spin: 1x 8B atomic load per thread, no barriers ---
    if (ew) {
      const unsigned long long* sp = Trd + sent_off;
      while ((unsigned)(__hip_atomic_load(sp, __ATOMIC_RELAXED, __HIP_MEMORY_SCOPE_AGENT) >> 32) < tgt) {}
    }
    __syncthreads();
    // --- verified tagged read of h(s) -> LDS (rarely retries now) ---
    {
      for (;;) {
        unsigned long long E0[6], E1[6];
        #pragma unroll
        for (int it = 0; it < 6; ++it) {
          int idx = it*384 + tid;                    // 2048 pair-tasks (2 entries each)
          if (idx < 2048) {
            const unsigned long long* pa = Trd + (size_t)(b0 + (idx >> 7))*256 + (idx & 127)*2;
            E0[it] = __hip_atomic_load(pa,     __ATOMIC_RELAXED, __HIP_MEMORY_SCOPE_AGENT);
            E1[it] = __hip_atomic_load(pa + 1, __ATOMIC_RELAXED, __HIP_MEMORY_SCOPE_AGENT);
          }
        }
        unsigned okm = 1u;
        #pragma unroll
        for (int it = 0; it < 6; ++it) {
          int idx = it*384 + tid;
          if (idx < 2048) {
            okm &= (unsigned)((E0[it] >> 32) >= tgt) & (unsigned)((E1[it] >> 32) >= tgt);
            int b = idx >> 7, j4 = (idx & 127)*4;
            u2v dv; dv[0] = (unsigned)E0[it]; dv[1] = (unsigned)E1[it];
            *(u2v*)&hlds[b][j4] = dv;
          }
        }
        unsigned long long bal = __ballot(okm != 0u);
        if (lane == 0) wok[wave] = (bal == ~0ull) ? 1u : 0u;
        __syncthreads();                               // also publishes hlds on success
        unsigned allok = wok[0] & wok[1] & wok[2] & wok[3] & wok[4] & wok[5];
        if (allok) break;
        __syncthreads();                               // WAR on wok before retry
      }
    }
    // --- gh slice: (16b x 16j) per wave over K=512 ---
    f4 acc = {0.f, 0.f, 0.f, 0.f};
    #pragma unroll
    for (int kk = 0; kk < 16; ++kk) {
      h8 af = *(const h8*)&hlds[lo][kk*32 + hi*8];
      h8 bf = *(const h8*)&wlds[gate][jh*16 + lo][kk*32 + hi*8];
      acc = __builtin_amdgcn_mfma_f32_16x16x32_f16(af, bf, acc, 0, 0, 0);
    }
    #pragma unroll
    for (int v = 0; v < 4; ++v)
      ghlds[gate][jh*16 + lo][hi*4 + v] = acc[v];   // [gate][j][b]
    __syncthreads();   // barB: ghlds RAW
    // --- elementwise GRU update + tagged h publish (fire-and-forget atomic) ---
    if (ew) {
      h2 pR = __builtin_bit_cast(h2, giR);
      h2 pZ = __builtin_bit_cast(h2, giZ);
      h2 pN = __builtin_bit_cast(h2, giN);
      h2 hnew; float hv[2];
      #pragma unroll
      for (int u = 0; u < 2; ++u) {
        float ir = (float)pR[u], iz = (float)pZ[u], inn = (float)pN[u];
        float hr = ghlds[0][2*ejp+u][eb] + bhr[u];
        float hz = ghlds[1][2*ejp+u][eb] + bhz[u];
        float hn = ghlds[2][2*ejp+u][eb] + bhn[u];
        float rr = 1.f/(1.f + __expf(-(ir + hr)));
        float zz = 1.f/(1.f + __expf(-(iz + hz)));
        float xx = inn + rr*hn;
        float nn = 1.f - 2.f/(__expf(2.f*xx) + 1.f);   // tanh, overflow-safe
        float h  = (1.f - zz)*nn + zz*hj[u];
        hj[u] = h; hnew[u] = (_Float16)h; hv[u] = h;
      }
      unsigned hu = __builtin_bit_cast(unsigned, hnew);
      unsigned long long ent = (unsigned long long)hu | ((unsigned long long)(s + 2) << 32);
      unsigned long long* ptr = Tb + (size_t)wpar*BB*256 + (size_t)(b0 + eb)*256 + (member*16 + ejp);
      __hip_atomic_store(ptr, ent, __ATOMIC_RELAXED, __HIP_MEMORY_SCOPE_AGENT);
      if (out_mid) {
        *(unsigned*)(out_mid + ((size_t)(b0+eb)*TL + t)*(size_t)(2*HH) + d*HH + ejA) = hu;
      } else {
        u2v ov; ov[0] = __builtin_bit_cast(unsigned, hv[0]); ov[1] = __builtin_bit_cast(unsigned, hv[1]);
        *(u2v*)(out_fin + ((size_t)(b0+eb)*TL + t)*(size_t)(2*HH) + d*HH + ejA) = ov;
      }
    }
    // no end barrier: next step's sentinel+read barriers provide separation
  }
  if (ew) {
    #pragma unroll
    for (int u = 0; u < 2; ++u)
      hn_out[((size_t)(2*layer + d)*BB + b0 + eb)*HH + ejA + u] = hj[u];
  }
}

// ---------------- host launcher ----------------
extern "C" void kernel_launch(void* const* d_in, const int* in_sizes, int n_in,
                              void* d_out, int out_size, void* d_ws, size_t ws_size,
                              hipStream_t stream) {
  (void)in_sizes; (void)n_in; (void)out_size;
  const float* x   = (const float*)d_in[0];
  const float* h0  = (const float*)d_in[1];
  const float* wih = (const float*)d_in[2];
  const float* whh = (const float*)d_in[3];
  const float* bih = (const float*)d_in[4];
  const float* bhh = (const float*)d_in[5];
  float* out = (float*)d_out;

  char* ws = (char*)d_ws;
  size_t off = 0;
  auto alloc = [&](size_t bytes) {
    char* p = ws + off;
    off += (bytes + 255) & ~(size_t)255;
    return p;
  };
  _Float16* x16   = (_Float16*)alloc((size_t)BT_*II*2);          // 128 MB
  _Float16* mid16 = (_Float16*)alloc((size_t)BT_*II*2);          // 128 MB
  _Float16* gi16  = (_Float16*)alloc((size_t)2*BT_*G3_*2);       // 384 MB
  _Float16* wih16 = (_Float16*)alloc((size_t)NL*N2_*II*2);       // 12 MB
  _Float16* whh16 = (_Float16*)alloc((size_t)NL*N2_*HH*2);       // 6 MB
  unsigned long long* tagh = (unsigned long long*)alloc((size_t)NL*2*2*BB*256*8); // 1 MB
  if (off > ws_size) {
    fprintf(stderr, "kernel_launch: workspace too small: need %zu have %zu\n", off, ws_size);
    return;
  }

  hipMemsetAsync(tagh, 0, (size_t)NL*2*2*BB*256*8, stream);      // clear stale tags (per replay)
  cvt_f2h<<<2048, 256, 0, stream>>>(x,   x16,   (size_t)BT_*II/4);
  cvt_f2h<<<512,  256, 0, stream>>>(wih, wih16, (size_t)NL*N2_*II/4);
  cvt_f2h<<<512,  256, 0, stream>>>(whh, whh16, (size_t)NL*N2_*HH/4);

  float* hn = out + (size_t)BT_*II;   // h_n region: (4,64,512) after (B,T,2H)

  // layer 0
  gemm_gi<<<dim3(24, 512), 256, 0, stream>>>(x16, wih16, bih, gi16);
  gru_layer<<<128, 384, 0, stream>>>(gi16, whh16, bhh, h0, tagh,
                                     mid16, nullptr, hn, 0);
  // layer 1
  gemm_gi<<<dim3(24, 512), 256, 0, stream>>>(mid16, wih16 + (size_t)N2_*II, bih + N2_, gi16);
  gru_layer<<<128, 384, 0, stream>>>(gi16, whh16 + (size_t)N2_*HH, bhh + N2_, h0,
                                     tagh + (size_t)2*2*BB*256, nullptr, out, hn, 1);
}

// Round 8
// 7192.872 us; speedup vs baseline: 5.1872x; 1.0789x over previous
//
#include <hip/hip_runtime.h>
#include <stdint.h>
#include <stdio.h>

// Problem constants
#define TL 1024          // T
#define BB 64            // B
#define HH 512           // H
#define II 1024          // input size (== 2H for layer 2)
#define NL 2             // layers
#define BT_ (BB*TL)      // 65536
#define G3_ 1536         // 3H
#define N2_ 3072         // 2*3H (both dirs stacked)

typedef _Float16 h8 __attribute__((ext_vector_type(8)));
typedef _Float16 h4 __attribute__((ext_vector_type(4)));
typedef _Float16 h2 __attribute__((ext_vector_type(2)));
typedef float    f4 __attribute__((ext_vector_type(4)));
typedef unsigned int u4 __attribute__((ext_vector_type(4)));
typedef unsigned int u2v __attribute__((ext_vector_type(2)));

// ---------------- fp32 -> fp16 convert ----------------
__global__ void cvt_f2h(const float* __restrict__ src, _Float16* __restrict__ dst, size_t n4) {
  size_t i = (size_t)blockIdx.x*blockDim.x + threadIdx.x;
  size_t stride = (size_t)gridDim.x*blockDim.x;
  for (; i < n4; i += stride) {
    f4 v = ((const f4*)src)[i];
    h4 o;
    o[0] = (_Float16)v[0]; o[1] = (_Float16)v[1];
    o[2] = (_Float16)v[2]; o[3] = (_Float16)v[3];
    ((h4*)dst)[i] = o;
  }
}

// ---------------- gi GEMM (unchanged, proven) ----------------
#define LDA 40
__launch_bounds__(256)
__global__ void gemm_gi(const _Float16* __restrict__ A, const _Float16* __restrict__ Bw,
                        const float* __restrict__ bias, _Float16* __restrict__ gi)
{
  const int bn = blockIdx.x, bm = blockIdx.y;
  const int tid = threadIdx.x;
  const int wave = tid >> 6, lane = tid & 63;
  const int wm = wave >> 1, wn = wave & 1;
  const int lo = lane & 15, hi = lane >> 4;
  __shared__ _Float16 As[128*LDA];
  __shared__ _Float16 Bs[128*LDA];
  f4 acc[4][4] = {};
  const int r0 = tid >> 2, c0 = (tid & 3)*8;
  const _Float16* Ag = A + (size_t)(bm*128)*II;
  const _Float16* Bg = Bw + (size_t)(bn*128)*II;
  u4 a0 = *(const u4*)(Ag + (size_t)r0*II + c0);
  u4 a1 = *(const u4*)(Ag + (size_t)(64+r0)*II + c0);
  u4 b0 = *(const u4*)(Bg + (size_t)r0*II + c0);
  u4 b1 = *(const u4*)(Bg + (size_t)(64+r0)*II + c0);
  for (int kt = 0; kt < 32; ++kt) {
    __syncthreads();
    *(u4*)&As[r0*LDA + c0] = a0;
    *(u4*)&As[(64+r0)*LDA + c0] = a1;
    *(u4*)&Bs[r0*LDA + c0] = b0;
    *(u4*)&Bs[(64+r0)*LDA + c0] = b1;
    if (kt+1 < 32) {
      const int off = (kt+1)*32 + c0;
      a0 = *(const u4*)(Ag + (size_t)r0*II + off);
      a1 = *(const u4*)(Ag + (size_t)(64+r0)*II + off);
      b0 = *(const u4*)(Bg + (size_t)r0*II + off);
      b1 = *(const u4*)(Bg + (size_t)(64+r0)*II + off);
    }
    __syncthreads();
    h8 af[4], bf[4];
    #pragma unroll
    for (int i = 0; i < 4; ++i)
      af[i] = *(const h8*)&As[(wm*64 + i*16 + lo)*LDA + hi*8];
    #pragma unroll
    for (int j = 0; j < 4; ++j)
      bf[j] = *(const h8*)&Bs[(wn*64 + j*16 + lo)*LDA + hi*8];
    #pragma unroll
    for (int i = 0; i < 4; ++i)
      #pragma unroll
      for (int j = 0; j < 4; ++j)
        acc[i][j] = __builtin_amdgcn_mfma_f32_16x16x32_f16(af[i], bf[j], acc[i][j], 0, 0, 0);
  }
  const int nbase = bn*128 + wn*64;
  const int mbase = bm*128 + wm*64;
  #pragma unroll
  for (int j = 0; j < 4; ++j) {
    int n = nbase + j*16 + lo;
    int dir = (n >= G3_) ? 1 : 0;
    int row = n - dir*G3_;
    float bs = bias[n];
    #pragma unroll
    for (int i = 0; i < 4; ++i) {
      int m0 = mbase + i*16 + hi*4;
      #pragma unroll
      for (int v = 0; v < 4; ++v)
        gi[((size_t)dir*BT_ + (size_t)(m0+v))*G3_ + row] = (_Float16)(acc[i][j][v] + bs);
    }
  }
}

// ---------------- persistent GRU layer kernel (tagged-mailbox, quad-pipelined read) ----------------
// 128 blocks. gg=bid&7: d=gg&1, g=gg>>1 (batch-chunk of 16). member=bid>>3 owns
// j-slice [member*32,+32), all 3 gates resident in LDS (96 rows W_hh).
// h exchange: 8B entries {h2 pair | tag<<32}, relaxed agent-scope 8B atomics
// (single-copy atomic; proven R6/R7). read step s: parity s&1, tag>=s+1; write
// end s: parity (s+1)&1, tag s+2, fire-and-forget. 2-step back-pressure: a
// writer's version-(s+2) publish is program-ordered after ALL its step-(s+1)
// reads, which gate on every member's version-(s+1) publish, which follows
// their complete step-s reads -> slot stable while readable (R6 induction).
// NEW (R8): all 16 entry loads issued up-front (parallel LLC RTs); members
// consumed in 4 quads: per-LANE tag verify with 32B thread-local retry (no
// block-wide re-reads/ballots - R7's hidden cost), stage quad to LDS, raw
// s_barrier + lgkmcnt(0) only (no vmcnt drain: later quads' loads stay in
// flight), MFMA the quad's 4 K-chunks. Barrier implies all lanes verified.
#define LDW 520
__launch_bounds__(384, 1)
__global__ void gru_layer(const _Float16* __restrict__ gi,     // [dir][b*T+t][1536]
                          const _Float16* __restrict__ whh,    // layer: [dir][1536][512]
                          const float* __restrict__ bhh,       // layer: [dir][1536]
                          const float* __restrict__ h0,        // [4][64][512]
                          unsigned long long* __restrict__ tagh, // layer: [d][par][64][256] u64
                          _Float16* __restrict__ out_mid,      // layer0: [b][t][1024] fp16
                          float* __restrict__ out_fin,         // layer1: [b][t][1024] fp32
                          float* __restrict__ hn_out,          // [4][64][512] fp32
                          int layer)
{
  const int bid = blockIdx.x;
  const int gg = bid & 7, d = gg & 1, g = gg >> 1;
  const int member = bid >> 3;
  const int j0 = member * 32, b0 = g * 16;
  const int tid = threadIdx.x;
  const int wave = tid >> 6, lane = tid & 63, lo = lane & 15, hi = lane >> 4;
  const int gate = wave >> 1, jh = wave & 1;     // 6 waves: 3 gates x 2 j-halves

  __shared__ _Float16 wlds[3][32][LDW];
  __shared__ _Float16 hlds[16][LDW];
  __shared__ float    ghlds[3][32][17];

  // --- load resident W_hh slice ---
  const _Float16* wsrc = whh + (size_t)d*G3_*HH;
  #pragma unroll
  for (int it = 0; it < 16; ++it) {
    int idx = it*384 + tid;
    int row = idx >> 6;
    int c8 = (idx & 63) * 8;
    int gt = row >> 5, jj = row & 31;
    u4 v = *(const u4*)(wsrc + (size_t)(gt*HH + j0 + jj)*HH + c8);
    *(u4*)&wlds[gt][jj][c8] = v;
  }

  const int ejp = tid & 15;              // j-pair within slice
  const int eb  = tid >> 4;              // 0..15 batch within chunk (ew threads)
  const bool ew = (tid < 256);
  const int ejA = j0 + 2*ejp;

  unsigned long long* Tb = tagh + (size_t)d*2*BB*256;   // this direction's 2 parities

  float hj[2];
  float bhr[2], bhz[2], bhn[2];

  if (ew) {
    #pragma unroll
    for (int u = 0; u < 2; ++u) {
      bhr[u] = bhh[(size_t)d*G3_ + 0*HH + ejA + u];
      bhz[u] = bhh[(size_t)d*G3_ + 1*HH + ejA + u];
      bhn[u] = bhh[(size_t)d*G3_ + 2*HH + ejA + u];
      hj[u]  = h0[((size_t)(2*layer + d)*BB + b0 + eb)*HH + ejA + u];
    }
    h2 p; p[0] = (_Float16)hj[0]; p[1] = (_Float16)hj[1];
    unsigned long long ent = (unsigned long long)__builtin_bit_cast(unsigned, p) | (1ull << 32);
    unsigned long long* ptr = Tb + (size_t)0*BB*256 + (size_t)(b0 + eb)*256 + (member*16 + ejp);
    __hip_atomic_store(ptr, ent, __ATOMIC_RELAXED, __HIP_MEMORY_SCOPE_AGENT);
  }
  __syncthreads();   // wlds ready

  for (int s = 0; s < TL; ++s) {
    const int t = d ? (TL-1 - s) : s;
    const int rpar = s & 1, wpar = rpar ^ 1;
    const unsigned tgt = (unsigned)(s + 1);
    const unsigned long long* Trd = Tb + (size_t)rpar*BB*256;
    unsigned giR = 0, giZ = 0, giN = 0;
    unsigned long long E[16];
    if (ew) {
      // gi for this step (HBM; retires first, hidden under mailbox RTs)
      const _Float16* p = gi + ((size_t)d*BT_ + (size_t)(b0 + eb)*TL + t)*(size_t)G3_ + ejA;
      giR = *(const unsigned*)(p);
      giZ = *(const unsigned*)(p + HH);
      giN = *(const unsigned*)(p + 2*HH);
      // issue ALL 16 mailbox entry loads up-front (4 quads x 4)
      #pragma unroll
      for (int q = 0; q < 4; ++q)
        #pragma unroll
        for (int k = 0; k < 4; ++k) {
          int i = tid*2 + (k >> 1);            // pair-task index 0..511
          E[q*4+k] = __hip_atomic_load(
              Trd + (size_t)(b0 + (i >> 5))*256 + q*64 + (i & 31)*2 + (k & 1),
              __ATOMIC_RELAXED, __HIP_MEMORY_SCOPE_AGENT);
        }
    }
    f4 acc = {0.f, 0.f, 0.f, 0.f};
    #pragma unroll
    for (int q = 0; q < 4; ++q) {
      if (ew) {
        // per-LANE verify + 32B thread-local retry (no barriers, no ballots)
        for (;;) {
          unsigned ok = 1u;
          #pragma unroll
          for (int k = 0; k < 4; ++k)
            ok &= (unsigned)((E[q*4+k] >> 32) >= tgt);
          if (ok) break;
          #pragma unroll
          for (int k = 0; k < 4; ++k) {
            int i = tid*2 + (k >> 1);
            E[q*4+k] = __hip_atomic_load(
                Trd + (size_t)(b0 + (i >> 5))*256 + q*64 + (i & 31)*2 + (k & 1),
                __ATOMIC_RELAXED, __HIP_MEMORY_SCOPE_AGENT);
          }
        }
        // stage quad q into hlds
        #pragma unroll
        for (int k = 0; k < 2; ++k) {
          int i = tid*2 + k;
          int b = i >> 5, p = i & 31;
          u2v dv; dv[0] = (unsigned)E[q*4 + k*2]; dv[1] = (unsigned)E[q*4 + k*2 + 1];
          *(u2v*)&hlds[b][q*128 + p*4] = dv;
        }
      }
      asm volatile("s_waitcnt lgkmcnt(0)" ::: "memory");   // ds_writes committed
      __builtin_amdgcn_s_barrier();                         // raw: vmcnt NOT drained
      __builtin_amdgcn_sched_barrier(0);
      // MFMA this quad's K-chunks
      #pragma unroll
      for (int kk = q*4; kk < q*4 + 4; ++kk) {
        h8 af = *(const h8*)&hlds[lo][kk*32 + hi*8];
        h8 bf = *(const h8*)&wlds[gate][jh*16 + lo][kk*32 + hi*8];
        acc = __builtin_amdgcn_mfma_f32_16x16x32_f16(af, bf, acc, 0, 0, 0);
      }
    }
    #pragma unroll
    for (int v = 0; v < 4; ++v)
      ghlds[gate][jh*16 + lo][hi*4 + v] = acc[v];   // [gate][j][b]
    __syncthreads();   // ghlds RAW (full drain fine; also frees hlds for next step)
    // --- elementwise GRU update + tagged h publish (fire-and-forget atomic) ---
    if (ew) {
      h2 pR = __builtin_bit_cast(h2, giR);
      h2 pZ = __builtin_bit_cast(h2, giZ);
      h2 pN = __builtin_bit_cast(h2, giN);
      h2 hnew; float hv[2];
      #pragma unroll
      for (int u = 0; u < 2; ++u) {
        float ir = (float)pR[u], iz = (float)pZ[u], inn = (float)pN[u];
        float hr = ghlds[0][2*ejp+u][eb] + bhr[u];
        float hz = ghlds[1][2*ejp+u][eb] + bhz[u];
        float hn = ghlds[2][2*ejp+u][eb] + bhn[u];
        float rr = 1.f/(1.f + __expf(-(ir + hr)));
        float zz = 1.f/(1.f + __expf(-(iz + hz)));
        float xx = inn + rr*hn;
        float nn = 1.f - 2.f/(__expf(2.f*xx) + 1.f);   // tanh, overflow-safe
        float h  = (1.f - zz)*nn + zz*hj[u];
        hj[u] = h; hnew[u] = (_Float16)h; hv[u] = h;
      }
      unsigned hu = __builtin_bit_cast(unsigned, hnew);
      unsigned long long ent = (unsigned long long)hu | ((unsigned long long)(s + 2) << 32);
      unsigned long long* ptr = Tb + (size_t)wpar*BB*256 + (size_t)(b0 + eb)*256 + (member*16 + ejp);
      __hip_atomic_store(ptr, ent, __ATOMIC_RELAXED, __HIP_MEMORY_SCOPE_AGENT);
      if (out_mid) {
        *(unsigned*)(out_mid + ((size_t)(b0+eb)*TL + t)*(size_t)(2*HH) + d*HH + ejA) = hu;
      } else {
        u2v ov; ov[0] = __builtin_bit_cast(unsigned, hv[0]); ov[1] = __builtin_bit_cast(unsigned, hv[1]);
        *(u2v*)(out_fin + ((size_t)(b0+eb)*TL + t)*(size_t)(2*HH) + d*HH + ejA) = ov;
      }
    }
    // no end barrier: next step's quad-0 barrier provides separation
  }
  if (ew) {
    #pragma unroll
    for (int u = 0; u < 2; ++u)
      hn_out[((size_t)(2*layer + d)*BB + b0 + eb)*HH + ejA + u] = hj[u];
  }
}

// ---------------- host launcher ----------------
extern "C" void kernel_launch(void* const* d_in, const int* in_sizes, int n_in,
                              void* d_out, int out_size, void* d_ws, size_t ws_size,
                              hipStream_t stream) {
  (void)in_sizes; (void)n_in; (void)out_size;
  const float* x   = (const float*)d_in[0];
  const float* h0  = (const float*)d_in[1];
  const float* wih = (const float*)d_in[2];
  const float* whh = (const float*)d_in[3];
  const float* bih = (const float*)d_in[4];
  const float* bhh = (const float*)d_in[5];
  float* out = (float*)d_out;

  char* ws = (char*)d_ws;
  size_t off = 0;
  auto alloc = [&](size_t bytes) {
    char* p = ws + off;
    off += (bytes + 255) & ~(size_t)255;
    return p;
  };
  _Float16* x16   = (_Float16*)alloc((size_t)BT_*II*2);          // 128 MB
  _Float16* mid16 = (_Float16*)alloc((size_t)BT_*II*2);          // 128 MB
  _Float16* gi16  = (_Float16*)alloc((size_t)2*BT_*G3_*2);       // 384 MB
  _Float16* wih16 = (_Float16*)alloc((size_t)NL*N2_*II*2);       // 12 MB
  _Float16* whh16 = (_Float16*)alloc((size_t)NL*N2_*HH*2);       // 6 MB
  unsigned long long* tagh = (unsigned long long*)alloc((size_t)NL*2*2*BB*256*8); // 1 MB
  if (off > ws_size) {
    fprintf(stderr, "kernel_launch: workspace too small: need %zu have %zu\n", off, ws_size);
    return;
  }

  hipMemsetAsync(tagh, 0, (size_t)NL*2*2*BB*256*8, stream);      // clear stale tags (per replay)
  cvt_f2h<<<2048, 256, 0, stream>>>(x,   x16,   (size_t)BT_*II/4);
  cvt_f2h<<<512,  256, 0, stream>>>(wih, wih16, (size_t)NL*N2_*II/4);
  cvt_f2h<<<512,  256, 0, stream>>>(whh, whh16, (size_t)NL*N2_*HH/4);

  float* hn = out + (size_t)BT_*II;   // h_n region: (4,64,512) after (B,T,2H)

  // layer 0
  gemm_gi<<<dim3(24, 512), 256, 0, stream>>>(x16, wih16, bih, gi16);
  gru_layer<<<128, 384, 0, stream>>>(gi16, whh16, bhh, h0, tagh,
                                     mid16, nullptr, hn, 0);
  // layer 1
  gemm_gi<<<dim3(24, 512), 256, 0, stream>>>(mid16, wih16 + (size_t)N2_*II, bih + N2_, gi16);
  gru_layer<<<128, 384, 0, stream>>>(gi16, whh16 + (size_t)N2_*HH, bhh + N2_, h0,
                                     tagh + (size_t)2*2*BB*256, nullptr, out, hn, 1);
}